// Round 2
// baseline (324.728 us; speedup 1.0000x reference)
//
#include <hip/hip_runtime.h>
#include <math.h>

// Problem constants
#define BB 512
#define TT 2048
#define AA 16
#define NTOT (512LL * 2048LL * 16LL)   // 16,777,216
#define GAMMA 0.99f
#define GLAM  0.9405f                  // gamma * lam, matches python double->f32
#define ENTC  1.4189385332046727f      // 0.5 + 0.5*log(2*pi)

#define NB3 2048                       // blocks for out kernel

typedef float f32x4 __attribute__((ext_vector_type(4)));

// ---------------------------------------------------------------------------
// K1: FUSED GAE + PPO objective. One block (512 threads) per batch row.
//
// Phase 1 (GAE): reversed affine recurrence y_u = a_u*y_{u-1} + b_u,
//   u = T-1-t. Each thread owns 4 consecutive u (16B-aligned t-chunks),
//   wave shuffle scan + LDS combine across the 8 waves. Result adv[t]
//   lands in LDS only -- no global adv buffer, no separate launch.
// Phase 2 (objective): the block streams its row's 5 x 128KB operand
//   slices with a depth-2 software pipeline (NT loads on single-use
//   streams; sigma cached for out_kernel), adv broadcast from LDS.
//   f64 block sum -> partials[b]. No atomics, no accumulator reset.
// ---------------------------------------------------------------------------
__device__ __forceinline__ float obj1(float x, float m, float s,
                                      float om, float os, float ad)
{
    float rs  = __builtin_amdgcn_rcpf(s);
    float ros = __builtin_amdgcn_rcpf(os);
    float z   = (x - m) * rs;
    float zo  = (x - om) * ros;
    float d   = 0.5f * (zo * zo - z * z);
    float ratio = os * rs * __expf(d);
    return fminf(ad * ratio, ad * 0.8f);     // clipped == 0.8 (faithful clip bug)
}

__device__ __forceinline__ double obj4d(f32x4 m, f32x4 s, f32x4 om, f32x4 os,
                                        f32x4 x, float ad)
{
    float o0 = obj1(x.x, m.x, s.x, om.x, os.x, ad);
    float o1 = obj1(x.y, m.y, s.y, om.y, os.y, ad);
    float o2 = obj1(x.z, m.z, s.z, om.z, os.z, ad);
    float o3 = obj1(x.w, m.w, s.w, om.w, os.w, ad);
    return (double)o0 + (double)o1 + (double)o2 + (double)o3;
}

__global__ __launch_bounds__(512, 4) void gae_obj_kernel(
    const float* __restrict__ rewards, const float* __restrict__ vout,
    const int* __restrict__ dones,
    const float* __restrict__ mu, const float* __restrict__ sigma,
    const float* __restrict__ old_mu, const float* __restrict__ old_sigma,
    const float* __restrict__ actions,
    double* __restrict__ partials)
{
    __shared__ float  adv_s[TT];          // 8 KB
    __shared__ float  wA[8], wB[8];
    __shared__ double wsum[8];

    const int b    = blockIdx.x;
    const int tid  = threadIdx.x;
    const int lane = tid & 63;
    const int wave = tid >> 6;

    // ---------------- Phase 1: GAE scan into LDS ----------------
    {
        const float* rw = rewards + (size_t)b * TT;
        const float* V  = vout    + (size_t)b * (TT + 1);
        const int*   dn = dones   + (size_t)b * TT;

        const int t_lo = TT - 4 - 4 * tid;          // multiple of 4, >= 0

        f32x4 r4 = *(const f32x4*)(rw + t_lo);
        int4  d4 = *(const int4*)(dn + t_lo);
        int   dt = (tid == 0) ? 1 : dn[t_lo + 4];   // dn[2048] OOB for tid 0; unused there
        float vv[5];
        #pragma unroll
        for (int j = 0; j < 5; ++j) vv[j] = V[t_lo + j];  // V[2048] valid (T+1 cols)

        float rr[4] = {r4.x, r4.y, r4.z, r4.w};
        int   dd[5] = {d4.x, d4.y, d4.z, d4.w, dt};

        float ak[4], bk[4];
        float SA = 1.f, SB = 0.f;                   // segment composite (earliest-first)
        #pragma unroll
        for (int k = 0; k < 4; ++k) {
            // u = tid*4 + k ; t = TT-1-u = t_lo + (3-k)
            const int j = 3 - k;
            float bu = rr[j] + GAMMA * vv[j + 1] - vv[j];
            float au = GLAM * (1.f - (float)dd[j + 1]);
            if (k == 0 && tid == 0) { au = 0.f; bu = 0.f; }   // u == 0
            ak[k] = au; bk[k] = bu;
            SB = au * SB + bu;
            SA = au * SA;
        }

        // wave-inclusive scan of composites
        #pragma unroll
        for (int off = 1; off < 64; off <<= 1) {
            float pA = __shfl_up(SA, off, 64);
            float pB = __shfl_up(SB, off, 64);
            if (lane >= off) { SB = SA * pB + SB; SA = SA * pA; }
        }

        if (lane == 63) { wA[wave] = SA; wB[wave] = SB; }
        __syncthreads();

        // composite of all waves before mine
        float PA = 1.f, PB = 0.f;
        for (int w = 0; w < wave; ++w) {
            float aw = wA[w], bw = wB[w];
            PB = aw * PB + bw;
            PA = aw * PA;
        }

        // exclusive within wave
        float EA = __shfl_up(SA, 1, 64);
        float EB = __shfl_up(SB, 1, 64);
        if (lane == 0) { EA = 1.f; EB = 0.f; }

        float x = EA * PB + EB;
        float outb[4];
        #pragma unroll
        for (int k = 0; k < 4; ++k) {
            x = ak[k] * x + bk[k];
            outb[3 - k] = x;                        // t = t_lo + (3-k)
        }
        *(f32x4*)(adv_s + t_lo) = (f32x4){outb[0], outb[1], outb[2], outb[3]};
    }
    __syncthreads();

    // ---------------- Phase 2: objective over this row ----------------
    const size_t rowf4 = (size_t)b * (TT * AA / 4);     // 8192 float4 per row
    const f32x4* m4  = (const f32x4*)mu        + rowf4;
    const f32x4* s4  = (const f32x4*)sigma     + rowf4;
    const f32x4* om4 = (const f32x4*)old_mu    + rowf4;
    const f32x4* os4 = (const f32x4*)old_sigma + rowf4;
    const f32x4* x4  = (const f32x4*)actions   + rowf4;

    uint32_t f = (uint32_t)tid;                         // row float4 index, step 512
    f32x4 m0  = __builtin_nontemporal_load(m4 + f);
    f32x4 s0  = s4[f];                                  // sigma stays cached for out_kernel
    f32x4 om0 = __builtin_nontemporal_load(om4 + f);
    f32x4 os0 = __builtin_nontemporal_load(os4 + f);
    f32x4 x0  = __builtin_nontemporal_load(x4 + f);
    float a0  = adv_s[f >> 2];

    double lsum = 0.0;
    #pragma unroll 1
    for (int it = 0; it < 15; ++it) {
        const uint32_t fn = f + 512u;
        f32x4 m1  = __builtin_nontemporal_load(m4 + fn);
        f32x4 s1  = s4[fn];
        f32x4 om1 = __builtin_nontemporal_load(om4 + fn);
        f32x4 os1 = __builtin_nontemporal_load(os4 + fn);
        f32x4 x1  = __builtin_nontemporal_load(x4 + fn);
        float a1  = adv_s[fn >> 2];

        lsum += obj4d(m0, s0, om0, os0, x0, a0);

        m0 = m1; s0 = s1; om0 = om1; os0 = os1; x0 = x1; a0 = a1; f = fn;
    }
    lsum += obj4d(m0, s0, om0, os0, x0, a0);

    // block reduce (8 waves)
    #pragma unroll
    for (int off = 32; off > 0; off >>= 1)
        lsum += __shfl_down(lsum, off, 64);
    if (lane == 0) wsum[wave] = lsum;
    __syncthreads();
    if (tid == 0) {
        double t = 0.0;
        #pragma unroll
        for (int w = 0; w < 8; ++w) t += wsum[w];
        partials[b] = t;
    }
}

// ---------------------------------------------------------------------------
// K2: out[i] = mean + log(sigma[i]) + ENTC.
// Each block re-reduces the 512 f64 partials itself (deterministic, no
// atomics, ~4KB L2-hit reads) then streams sigma -> out with two
// independent streams x depth-2 pipeline (4 loads in flight per wave).
// ---------------------------------------------------------------------------
__global__ __launch_bounds__(256) void out_kernel(
    const float* __restrict__ sigma, const double* __restrict__ partials,
    float* __restrict__ out)
{
    const int tid  = threadIdx.x;
    const int lane = tid & 63, wave = tid >> 6;

    // block-local mean from the 512 partials
    double s = partials[tid] + partials[tid + 256];
    #pragma unroll
    for (int off = 32; off > 0; off >>= 1)
        s += __shfl_down(s, off, 64);
    __shared__ double wsum[4];
    __shared__ float  mean_s;
    if (lane == 0) wsum[wave] = s;
    __syncthreads();
    if (tid == 0)
        mean_s = (float)((wsum[0] + wsum[1] + wsum[2] + wsum[3]) / (double)NTOT);
    __syncthreads();
    const float mean = mean_s;

    const uint32_t HALF = (uint32_t)(NTOT / 4 / 2);     // 2,097,152 float4
    const uint32_t STEP = (uint32_t)NB3 * 256u;         // 524,288 threads
    uint32_t v = (uint32_t)blockIdx.x * 256u + (uint32_t)tid;

    const f32x4* s4 = (const f32x4*)sigma;
    f32x4* o4 = (f32x4*)out;

    f32x4 a0 = s4[v];
    f32x4 b0 = s4[v + HALF];
    #pragma unroll 1
    for (int it = 0; it < 3; ++it) {
        const uint32_t vn = v + STEP;
        f32x4 a1 = s4[vn];
        f32x4 b1 = s4[vn + HALF];

        f32x4 oa, ob;
        oa.x = mean + __logf(a0.x) + ENTC;  oa.y = mean + __logf(a0.y) + ENTC;
        oa.z = mean + __logf(a0.z) + ENTC;  oa.w = mean + __logf(a0.w) + ENTC;
        ob.x = mean + __logf(b0.x) + ENTC;  ob.y = mean + __logf(b0.y) + ENTC;
        ob.z = mean + __logf(b0.z) + ENTC;  ob.w = mean + __logf(b0.w) + ENTC;
        __builtin_nontemporal_store(oa, o4 + v);
        __builtin_nontemporal_store(ob, o4 + v + HALF);

        a0 = a1; b0 = b1; v = vn;
    }
    f32x4 oa, ob;
    oa.x = mean + __logf(a0.x) + ENTC;  oa.y = mean + __logf(a0.y) + ENTC;
    oa.z = mean + __logf(a0.z) + ENTC;  oa.w = mean + __logf(a0.w) + ENTC;
    ob.x = mean + __logf(b0.x) + ENTC;  ob.y = mean + __logf(b0.y) + ENTC;
    ob.z = mean + __logf(b0.z) + ENTC;  ob.w = mean + __logf(b0.w) + ENTC;
    __builtin_nontemporal_store(oa, o4 + v);
    __builtin_nontemporal_store(ob, o4 + v + HALF);
}

// ---------------------------------------------------------------------------
extern "C" void kernel_launch(void* const* d_in, const int* in_sizes, int n_in,
                              void* d_out, int out_size, void* d_ws, size_t ws_size,
                              hipStream_t stream) {
    const float* rewards   = (const float*)d_in[0];   // [B,T]
    const float* critic    = (const float*)d_in[1];   // [B,T+1]
    const float* mu        = (const float*)d_in[2];   // [B,T,A]
    const float* sigma     = (const float*)d_in[3];
    const float* old_mu    = (const float*)d_in[4];
    const float* old_sigma = (const float*)d_in[5];
    const float* actions   = (const float*)d_in[6];
    const int*   dones     = (const int*)d_in[7];     // [B,T]
    float* out = (float*)d_out;

    double* partials = (double*)d_ws;                 // 512 * 8 B

    gae_obj_kernel<<<BB, 512, 0, stream>>>(rewards, critic, dones,
                                           mu, sigma, old_mu, old_sigma,
                                           actions, partials);
    out_kernel<<<NB3, 256, 0, stream>>>(sigma, partials, out);
}

// Round 4
// 321.976 us; speedup vs baseline: 1.0085x; 1.0085x over previous
//
#include <hip/hip_runtime.h>
#include <math.h>

// Problem constants
#define BB 512
#define TT 2048
#define AA 16
#define NTOT (512LL * 2048LL * 16LL)   // 16,777,216
#define GAMMA 0.99f
#define GLAM  0.9405f                  // gamma * lam, matches python double->f32
#define ENTC  1.4189385332046727f      // 0.5 + 0.5*log(2*pi)

#define QPB 4                          // blocks per batch row (phase-2 split)
#define NB1 (BB * QPB)                 // 2048 blocks for fused kernel
#define NB3 4096                       // blocks for out kernel

typedef float f32x4 __attribute__((ext_vector_type(4)));

// ---------------------------------------------------------------------------
// K1: FUSED GAE + PPO objective. FOUR blocks (512 threads) per batch row.
// All 4 blocks of a row redundantly compute the full-row GAE scan into LDS
// (~24KB of redundant reads, L3-absorbed; buys 4x phase-2 parallelism with
// no global adv round-trip and no extra launch). Each block then streams
// its QUARTER of the row's 5 operand slices.
//
// Phase-2 pipeline: ping-pong NAMED register buffers A/B (no rotation
// copies -- those forced an end-of-iteration load drain and let regalloc
// collapse the pipeline to VGPR=24 / 1 load in flight last round) with
// sched_barrier(0) fences so the scheduler cannot sink the load clusters.
// ---------------------------------------------------------------------------
__device__ __forceinline__ float obj1(float x, float m, float s,
                                      float om, float os, float ad)
{
    float rs  = __builtin_amdgcn_rcpf(s);
    float ros = __builtin_amdgcn_rcpf(os);
    float z   = (x - m) * rs;
    float zo  = (x - om) * ros;
    float d   = 0.5f * (zo * zo - z * z);
    float ratio = os * rs * __expf(d);
    return fminf(ad * ratio, ad * 0.8f);     // clipped == 0.8 (faithful clip bug)
}

__device__ __forceinline__ double obj4d(f32x4 m, f32x4 s, f32x4 om, f32x4 os,
                                        f32x4 x, float ad)
{
    float o0 = obj1(x.x, m.x, s.x, om.x, os.x, ad);
    float o1 = obj1(x.y, m.y, s.y, om.y, os.y, ad);
    float o2 = obj1(x.z, m.z, s.z, om.z, os.z, ad);
    float o3 = obj1(x.w, m.w, s.w, om.w, os.w, ad);
    return (double)o0 + (double)o1 + (double)o2 + (double)o3;
}

__global__ __launch_bounds__(512) void gae_obj_kernel(
    const float* __restrict__ rewards, const float* __restrict__ vout,
    const int* __restrict__ dones,
    const float* __restrict__ mu, const float* __restrict__ sigma,
    const float* __restrict__ old_mu, const float* __restrict__ old_sigma,
    const float* __restrict__ actions,
    double* __restrict__ partials)
{
    __shared__ float  adv_s[TT];          // 8 KB
    __shared__ float  wA[8], wB[8];
    __shared__ double wsum[8];

    const int b    = blockIdx.x >> 2;     // batch row
    const int q    = blockIdx.x & 3;      // quarter of the row
    const int tid  = threadIdx.x;
    const int lane = tid & 63;
    const int wave = tid >> 6;

    // ---------------- Phase 1: full-row GAE scan into LDS ----------------
    {
        const float* rw = rewards + (size_t)b * TT;
        const float* V  = vout    + (size_t)b * (TT + 1);
        const int*   dn = dones   + (size_t)b * TT;

        const int t_lo = TT - 4 - 4 * tid;          // multiple of 4, >= 0

        f32x4 r4 = *(const f32x4*)(rw + t_lo);
        int4  d4 = *(const int4*)(dn + t_lo);
        int   dt = (tid == 0) ? 1 : dn[t_lo + 4];   // dn[2048] OOB for tid 0; unused there
        float vv[5];
        #pragma unroll
        for (int j = 0; j < 5; ++j) vv[j] = V[t_lo + j];  // V[2048] valid (T+1 cols)

        float rr[4] = {r4.x, r4.y, r4.z, r4.w};
        int   dd[5] = {d4.x, d4.y, d4.z, d4.w, dt};

        float ak[4], bk[4];
        float SA = 1.f, SB = 0.f;                   // segment composite (earliest-first)
        #pragma unroll
        for (int k = 0; k < 4; ++k) {
            // u = tid*4 + k ; t = TT-1-u = t_lo + (3-k)
            const int j = 3 - k;
            float bu = rr[j] + GAMMA * vv[j + 1] - vv[j];
            float au = GLAM * (1.f - (float)dd[j + 1]);
            if (k == 0 && tid == 0) { au = 0.f; bu = 0.f; }   // u == 0
            ak[k] = au; bk[k] = bu;
            SB = au * SB + bu;
            SA = au * SA;
        }

        // wave-inclusive scan of composites
        #pragma unroll
        for (int off = 1; off < 64; off <<= 1) {
            float pA = __shfl_up(SA, off, 64);
            float pB = __shfl_up(SB, off, 64);
            if (lane >= off) { SB = SA * pB + SB; SA = SA * pA; }
        }

        if (lane == 63) { wA[wave] = SA; wB[wave] = SB; }
        __syncthreads();

        // composite of all waves before mine
        float PA = 1.f, PB = 0.f;
        for (int w = 0; w < wave; ++w) {
            float aw = wA[w], bw = wB[w];
            PB = aw * PB + bw;
            PA = aw * PA;
        }

        // exclusive within wave
        float EA = __shfl_up(SA, 1, 64);
        float EB = __shfl_up(SB, 1, 64);
        if (lane == 0) { EA = 1.f; EB = 0.f; }

        float x = EA * PB + EB;
        float outb[4];
        #pragma unroll
        for (int k = 0; k < 4; ++k) {
            x = ak[k] * x + bk[k];
            outb[3 - k] = x;                        // t = t_lo + (3-k)
        }
        *(f32x4*)(adv_s + t_lo) = (f32x4){outb[0], outb[1], outb[2], outb[3]};
    }
    __syncthreads();

    // ---------------- Phase 2: objective over this block's quarter --------
    // Row has 8192 float4; quarter q covers [q*2048, (q+1)*2048).
    const size_t basef4 = (size_t)b * 8192 + (size_t)q * 2048;
    const f32x4* m4  = (const f32x4*)mu        + basef4;
    const f32x4* s4  = (const f32x4*)sigma     + basef4;
    const f32x4* om4 = (const f32x4*)old_mu    + basef4;
    const f32x4* os4 = (const f32x4*)old_sigma + basef4;
    const f32x4* x4  = (const f32x4*)actions   + basef4;
    const float* advq = adv_s + q * 512;            // adv index within quarter

    const uint32_t f0 = (uint32_t)tid;
    const uint32_t f1 = f0 + 512u;
    const uint32_t f2 = f0 + 1024u;
    const uint32_t f3 = f0 + 1536u;

    f32x4 Am, As, Aom, Aos, Ax; float Aa;
    f32x4 Bm, Bs, Bom, Bos, Bx; float Ba;

    auto LOADC = [&](uint32_t f, f32x4& m, f32x4& s, f32x4& om, f32x4& os,
                     f32x4& x, float& a) {
        m  = __builtin_nontemporal_load(m4 + f);
        s  = s4[f];                                  // sigma stays cached for out_kernel
        om = __builtin_nontemporal_load(om4 + f);
        os = __builtin_nontemporal_load(os4 + f);
        x  = __builtin_nontemporal_load(x4 + f);
        a  = advq[f >> 2];
    };

    LOADC(f0, Am, As, Aom, Aos, Ax, Aa);
    LOADC(f1, Bm, Bs, Bom, Bos, Bx, Ba);
    __builtin_amdgcn_sched_barrier(0);
    double lsum = obj4d(Am, As, Aom, Aos, Ax, Aa);
    LOADC(f2, Am, As, Aom, Aos, Ax, Aa);
    __builtin_amdgcn_sched_barrier(0);
    lsum += obj4d(Bm, Bs, Bom, Bos, Bx, Ba);
    LOADC(f3, Bm, Bs, Bom, Bos, Bx, Ba);
    __builtin_amdgcn_sched_barrier(0);
    lsum += obj4d(Am, As, Aom, Aos, Ax, Aa);
    lsum += obj4d(Bm, Bs, Bom, Bos, Bx, Ba);

    // block reduce (8 waves)
    #pragma unroll
    for (int off = 32; off > 0; off >>= 1)
        lsum += __shfl_down(lsum, off, 64);
    if (lane == 0) wsum[wave] = lsum;
    __syncthreads();
    if (tid == 0) {
        double t = 0.0;
        #pragma unroll
        for (int w = 0; w < 8; ++w) t += wsum[w];
        partials[blockIdx.x] = t;
    }
}

// ---------------------------------------------------------------------------
// K2: out[i] = mean + log(sigma[i]) + ENTC.
// Each block re-reduces the 2048 f64 partials itself (L2/L3-hit reads,
// deterministic, no atomics), then each thread processes 4 INDEPENDENT
// float4 streams issued back-to-back -- pure MLP, nothing loop-carried.
// ---------------------------------------------------------------------------
__global__ __launch_bounds__(256) void out_kernel(
    const float* __restrict__ sigma, const double* __restrict__ partials,
    float* __restrict__ out)
{
    const int tid  = threadIdx.x;
    const int lane = tid & 63, wave = tid >> 6;

    // block-local mean from the 2048 partials
    double s = 0.0;
    #pragma unroll
    for (int i = 0; i < 8; ++i) s += partials[tid + 256 * i];
    #pragma unroll
    for (int off = 32; off > 0; off >>= 1)
        s += __shfl_down(s, off, 64);
    __shared__ double wsum[4];
    __shared__ float  mc_s;
    if (lane == 0) wsum[wave] = s;
    __syncthreads();
    if (tid == 0)
        mc_s = (float)((wsum[0] + wsum[1] + wsum[2] + wsum[3]) / (double)NTOT)
               + ENTC;
    __syncthreads();
    const float mc = mc_s;                       // mean + ENTC

    const uint32_t Q = (uint32_t)(NTOT / 4 / 4);  // 1,048,576 float4 per stream
    const uint32_t v = (uint32_t)blockIdx.x * 256u + (uint32_t)tid;  // < Q

    const f32x4* s4 = (const f32x4*)sigma;
    f32x4* o4 = (f32x4*)out;

    f32x4 a = s4[v];
    f32x4 b = s4[v + Q];
    f32x4 c = s4[v + 2 * Q];
    f32x4 d = s4[v + 3 * Q];
    __builtin_amdgcn_sched_barrier(0);

    f32x4 oa, ob, oc, od;
    oa.x = mc + __logf(a.x);  oa.y = mc + __logf(a.y);
    oa.z = mc + __logf(a.z);  oa.w = mc + __logf(a.w);
    ob.x = mc + __logf(b.x);  ob.y = mc + __logf(b.y);
    ob.z = mc + __logf(b.z);  ob.w = mc + __logf(b.w);
    oc.x = mc + __logf(c.x);  oc.y = mc + __logf(c.y);
    oc.z = mc + __logf(c.z);  oc.w = mc + __logf(c.w);
    od.x = mc + __logf(d.x);  od.y = mc + __logf(d.y);
    od.z = mc + __logf(d.z);  od.w = mc + __logf(d.w);

    __builtin_nontemporal_store(oa, o4 + v);
    __builtin_nontemporal_store(ob, o4 + v + Q);
    __builtin_nontemporal_store(oc, o4 + v + 2 * Q);
    __builtin_nontemporal_store(od, o4 + v + 3 * Q);
}

// ---------------------------------------------------------------------------
extern "C" void kernel_launch(void* const* d_in, const int* in_sizes, int n_in,
                              void* d_out, int out_size, void* d_ws, size_t ws_size,
                              hipStream_t stream) {
    const float* rewards   = (const float*)d_in[0];   // [B,T]
    const float* critic    = (const float*)d_in[1];   // [B,T+1]
    const float* mu        = (const float*)d_in[2];   // [B,T,A]
    const float* sigma     = (const float*)d_in[3];
    const float* old_mu    = (const float*)d_in[4];
    const float* old_sigma = (const float*)d_in[5];
    const float* actions   = (const float*)d_in[6];
    const int*   dones     = (const int*)d_in[7];     // [B,T]
    float* out = (float*)d_out;

    double* partials = (double*)d_ws;                 // NB1 * 8 B = 16 KB

    gae_obj_kernel<<<NB1, 512, 0, stream>>>(rewards, critic, dones,
                                            mu, sigma, old_mu, old_sigma,
                                            actions, partials);
    out_kernel<<<NB3, 256, 0, stream>>>(sigma, partials, out);
}

// Round 5
// 319.298 us; speedup vs baseline: 1.0170x; 1.0084x over previous
//
#include <hip/hip_runtime.h>
#include <math.h>

// Problem constants
#define BB 512
#define TT 2048
#define AA 16
#define NTOT (512LL * 2048LL * 16LL)   // 16,777,216
#define GAMMA 0.99f
#define GLAM  0.9405f                  // gamma * lam, matches python double->f32
#define ENTC  1.4189385332046727f      // 0.5 + 0.5*log(2*pi)

#define QPB 4                          // blocks per batch row (phase-2 split)
#define NB1 (BB * QPB)                 // 2048 blocks for fused kernel
#define NB3 2048                       // blocks for out kernel (8 f32x4/thread)

typedef float f32x4 __attribute__((ext_vector_type(4)));

// Volatile-asm 16B global loads: cannot be deleted, reordered among
// themselves, or liveness-collapsed by regalloc (rounds 1/2/4 showed the
// compiler collapsing every source-level pipeline to VGPR<=32 / ~1 load
// in flight). saddr form: 64-bit SGPR base + 32-bit VGPR byte offset.
#define NT_LOAD(dst, off, base) \
    asm volatile("global_load_dwordx4 %0, %1, %2 nt" \
                 : "=v"(dst) : "v"(off), "s"(base))
#define C_LOAD(dst, off, base) \
    asm volatile("global_load_dwordx4 %0, %1, %2" \
                 : "=v"(dst) : "v"(off), "s"(base))
// Counted drain + scheduling fence (rule #18: hipcc will hoist
// register-only compute above a bare asm waitcnt without the fence).
#define VM_WAIT_FENCE(n) do { \
    asm volatile("s_waitcnt vmcnt(" #n ")"); \
    __builtin_amdgcn_sched_barrier(0); } while (0)

// ---------------------------------------------------------------------------
__device__ __forceinline__ float obj1(float x, float m, float s,
                                      float om, float os, float ad)
{
    float rs  = __builtin_amdgcn_rcpf(s);
    float ros = __builtin_amdgcn_rcpf(os);
    float z   = (x - m) * rs;
    float zo  = (x - om) * ros;
    float d   = 0.5f * (zo * zo - z * z);
    float ratio = os * rs * __expf(d);
    return fminf(ad * ratio, ad * 0.8f);     // clipped == 0.8 (faithful clip bug)
}

__device__ __forceinline__ double obj4d(f32x4 m, f32x4 s, f32x4 om, f32x4 os,
                                        f32x4 x, float ad)
{
    float o0 = obj1(x.x, m.x, s.x, om.x, os.x, ad);
    float o1 = obj1(x.y, m.y, s.y, om.y, os.y, ad);
    float o2 = obj1(x.z, m.z, s.z, om.z, os.z, ad);
    float o3 = obj1(x.w, m.w, s.w, om.w, os.w, ad);
    return (double)o0 + (double)o1 + (double)o2 + (double)o3;
}

// ---------------------------------------------------------------------------
// K1: FUSED GAE + PPO objective. Four blocks (512 threads) per batch row;
// all 4 redundantly scan the full row into LDS (L3-absorbed), then each
// streams its quarter with 20 asm loads in flight per thread.
// ---------------------------------------------------------------------------
__global__ __launch_bounds__(512) void gae_obj_kernel(
    const float* __restrict__ rewards, const float* __restrict__ vout,
    const int* __restrict__ dones,
    const float* __restrict__ mu, const float* __restrict__ sigma,
    const float* __restrict__ old_mu, const float* __restrict__ old_sigma,
    const float* __restrict__ actions,
    double* __restrict__ partials)
{
    __shared__ float  adv_s[TT];          // 8 KB
    __shared__ float  wA[8], wB[8];
    __shared__ double wsum[8];

    const int b    = blockIdx.x >> 2;     // batch row
    const int q    = blockIdx.x & 3;      // quarter of the row
    const int tid  = threadIdx.x;
    const int lane = tid & 63;
    const int wave = tid >> 6;

    // ---------------- Phase 1: full-row GAE scan into LDS ----------------
    {
        const float* rw = rewards + (size_t)b * TT;
        const float* V  = vout    + (size_t)b * (TT + 1);
        const int*   dn = dones   + (size_t)b * TT;

        const int t_lo = TT - 4 - 4 * tid;          // multiple of 4, >= 0

        f32x4 r4 = *(const f32x4*)(rw + t_lo);
        int4  d4 = *(const int4*)(dn + t_lo);
        int   dt = (tid == 0) ? 1 : dn[t_lo + 4];   // dn[2048] OOB for tid 0; unused there
        float vv[5];
        #pragma unroll
        for (int j = 0; j < 5; ++j) vv[j] = V[t_lo + j];  // V[2048] valid (T+1 cols)

        float rr[4] = {r4.x, r4.y, r4.z, r4.w};
        int   dd[5] = {d4.x, d4.y, d4.z, d4.w, dt};

        float ak[4], bk[4];
        float SA = 1.f, SB = 0.f;                   // segment composite (earliest-first)
        #pragma unroll
        for (int k = 0; k < 4; ++k) {
            // u = tid*4 + k ; t = TT-1-u = t_lo + (3-k)
            const int j = 3 - k;
            float bu = rr[j] + GAMMA * vv[j + 1] - vv[j];
            float au = GLAM * (1.f - (float)dd[j + 1]);
            if (k == 0 && tid == 0) { au = 0.f; bu = 0.f; }   // u == 0
            ak[k] = au; bk[k] = bu;
            SB = au * SB + bu;
            SA = au * SA;
        }

        #pragma unroll
        for (int off = 1; off < 64; off <<= 1) {
            float pA = __shfl_up(SA, off, 64);
            float pB = __shfl_up(SB, off, 64);
            if (lane >= off) { SB = SA * pB + SB; SA = SA * pA; }
        }

        if (lane == 63) { wA[wave] = SA; wB[wave] = SB; }
        __syncthreads();

        float PA = 1.f, PB = 0.f;
        for (int w = 0; w < wave; ++w) {
            float aw = wA[w], bw = wB[w];
            PB = aw * PB + bw;
            PA = aw * PA;
        }

        float EA = __shfl_up(SA, 1, 64);
        float EB = __shfl_up(SB, 1, 64);
        if (lane == 0) { EA = 1.f; EB = 0.f; }

        float x = EA * PB + EB;
        float outb[4];
        #pragma unroll
        for (int k = 0; k < 4; ++k) {
            x = ak[k] * x + bk[k];
            outb[3 - k] = x;                        // t = t_lo + (3-k)
        }
        *(f32x4*)(adv_s + t_lo) = (f32x4){outb[0], outb[1], outb[2], outb[3]};
    }
    __syncthreads();

    // ---------------- Phase 2: objective over this block's quarter --------
    // Row = 8192 float4; quarter q covers [q*2048, (q+1)*2048).
    const size_t basef4 = (size_t)b * 8192 + (size_t)q * 2048;
    const f32x4* m4  = (const f32x4*)mu        + basef4;
    const f32x4* s4  = (const f32x4*)sigma     + basef4;
    const f32x4* om4 = (const f32x4*)old_mu    + basef4;
    const f32x4* os4 = (const f32x4*)old_sigma + basef4;
    const f32x4* x4  = (const f32x4*)actions   + basef4;
    const float* advq = adv_s + q * 512;

    // adv values from LDS (lgkmcnt handled by compiler)
    const int ai = tid >> 2;
    const float Aa = advq[ai];
    const float Ba = advq[ai + 128];
    const float Ca = advq[ai + 256];
    const float Da = advq[ai + 384];

    // byte offsets of the 4 clusters (f = tid + 512k, *16 bytes)
    const uint32_t o0 = (uint32_t)tid * 16u;
    const uint32_t o1 = o0 + 512u * 16u;
    const uint32_t o2 = o0 + 1024u * 16u;
    const uint32_t o3 = o0 + 1536u * 16u;

    f32x4 Am, As, Aom, Aos, Ax;
    f32x4 Bm, Bs, Bom, Bos, Bx;
    f32x4 Cm, Cs, Com, Cos, Cx;
    f32x4 Dm, Ds, Dom, Dos, Dx;

    // 20 loads in flight per thread (~20KB per wave)
    NT_LOAD(Am, o0, m4);  C_LOAD(As, o0, s4);  NT_LOAD(Aom, o0, om4);
    NT_LOAD(Aos, o0, os4);  NT_LOAD(Ax, o0, x4);
    NT_LOAD(Bm, o1, m4);  C_LOAD(Bs, o1, s4);  NT_LOAD(Bom, o1, om4);
    NT_LOAD(Bos, o1, os4);  NT_LOAD(Bx, o1, x4);
    NT_LOAD(Cm, o2, m4);  C_LOAD(Cs, o2, s4);  NT_LOAD(Com, o2, om4);
    NT_LOAD(Cos, o2, os4);  NT_LOAD(Cx, o2, x4);
    NT_LOAD(Dm, o3, m4);  C_LOAD(Ds, o3, s4);  NT_LOAD(Dom, o3, om4);
    NT_LOAD(Dos, o3, os4);  NT_LOAD(Dx, o3, x4);

    VM_WAIT_FENCE(15);                       // cluster A landed
    double lsum = obj4d(Am, As, Aom, Aos, Ax, Aa);
    VM_WAIT_FENCE(10);                       // cluster B landed
    lsum += obj4d(Bm, Bs, Bom, Bos, Bx, Ba);
    VM_WAIT_FENCE(5);                        // cluster C landed
    lsum += obj4d(Cm, Cs, Com, Cos, Cx, Ca);
    VM_WAIT_FENCE(0);                        // cluster D landed
    lsum += obj4d(Dm, Ds, Dom, Dos, Dx, Da);

    // block reduce (8 waves)
    #pragma unroll
    for (int off = 32; off > 0; off >>= 1)
        lsum += __shfl_down(lsum, off, 64);
    if (lane == 0) wsum[wave] = lsum;
    __syncthreads();
    if (tid == 0) {
        double t = 0.0;
        #pragma unroll
        for (int w = 0; w < 8; ++w) t += wsum[w];
        partials[blockIdx.x] = t;
    }
}

// ---------------------------------------------------------------------------
// K2: out[i] = mean + log(sigma[i]) + ENTC.
// 8 asm loads issued FIRST (their HBM latency hides under the partials
// reduce), then one drain, compute, NT stores. 2048 blocks x 256 thr x 8.
// ---------------------------------------------------------------------------
__global__ __launch_bounds__(256) void out_kernel(
    const float* __restrict__ sigma, const double* __restrict__ partials,
    float* __restrict__ out)
{
    const int tid  = threadIdx.x;
    const int lane = tid & 63, wave = tid >> 6;

    const uint32_t Q = (uint32_t)(NTOT / 4 / 8);        // 524,288 f32x4/stream
    const uint32_t v = (uint32_t)blockIdx.x * 256u + (uint32_t)tid;  // < Q
    const f32x4* s4 = (const f32x4*)sigma;
    f32x4* o4 = (f32x4*)out;

    f32x4 a0, a1, a2, a3, a4, a5, a6, a7;
    C_LOAD(a0, (v + 0u * Q) * 16u, s4);
    C_LOAD(a1, (v + 1u * Q) * 16u, s4);
    C_LOAD(a2, (v + 2u * Q) * 16u, s4);
    C_LOAD(a3, (v + 3u * Q) * 16u, s4);
    C_LOAD(a4, (v + 4u * Q) * 16u, s4);
    C_LOAD(a5, (v + 5u * Q) * 16u, s4);
    C_LOAD(a6, (v + 6u * Q) * 16u, s4);
    C_LOAD(a7, (v + 7u * Q) * 16u, s4);

    // partials reduce runs while the 8 stream loads are in flight
    double s = 0.0;
    #pragma unroll
    for (int i = 0; i < 8; ++i) s += partials[tid + 256 * i];
    #pragma unroll
    for (int off = 32; off > 0; off >>= 1)
        s += __shfl_down(s, off, 64);
    __shared__ double wsum[4];
    __shared__ float  mc_s;
    if (lane == 0) wsum[wave] = s;
    __syncthreads();
    if (tid == 0)
        mc_s = (float)((wsum[0] + wsum[1] + wsum[2] + wsum[3]) / (double)NTOT)
               + ENTC;
    __syncthreads();
    const float mc = mc_s;                       // mean + ENTC

    VM_WAIT_FENCE(0);                            // all 8 streams landed

    f32x4 r0, r1, r2, r3, r4, r5, r6, r7;
    r0.x = mc + __logf(a0.x); r0.y = mc + __logf(a0.y);
    r0.z = mc + __logf(a0.z); r0.w = mc + __logf(a0.w);
    r1.x = mc + __logf(a1.x); r1.y = mc + __logf(a1.y);
    r1.z = mc + __logf(a1.z); r1.w = mc + __logf(a1.w);
    r2.x = mc + __logf(a2.x); r2.y = mc + __logf(a2.y);
    r2.z = mc + __logf(a2.z); r2.w = mc + __logf(a2.w);
    r3.x = mc + __logf(a3.x); r3.y = mc + __logf(a3.y);
    r3.z = mc + __logf(a3.z); r3.w = mc + __logf(a3.w);
    r4.x = mc + __logf(a4.x); r4.y = mc + __logf(a4.y);
    r4.z = mc + __logf(a4.z); r4.w = mc + __logf(a4.w);
    r5.x = mc + __logf(a5.x); r5.y = mc + __logf(a5.y);
    r5.z = mc + __logf(a5.z); r5.w = mc + __logf(a5.w);
    r6.x = mc + __logf(a6.x); r6.y = mc + __logf(a6.y);
    r6.z = mc + __logf(a6.z); r6.w = mc + __logf(a6.w);
    r7.x = mc + __logf(a7.x); r7.y = mc + __logf(a7.y);
    r7.z = mc + __logf(a7.z); r7.w = mc + __logf(a7.w);

    __builtin_nontemporal_store(r0, o4 + v + 0u * Q);
    __builtin_nontemporal_store(r1, o4 + v + 1u * Q);
    __builtin_nontemporal_store(r2, o4 + v + 2u * Q);
    __builtin_nontemporal_store(r3, o4 + v + 3u * Q);
    __builtin_nontemporal_store(r4, o4 + v + 4u * Q);
    __builtin_nontemporal_store(r5, o4 + v + 5u * Q);
    __builtin_nontemporal_store(r6, o4 + v + 6u * Q);
    __builtin_nontemporal_store(r7, o4 + v + 7u * Q);
}

// ---------------------------------------------------------------------------
extern "C" void kernel_launch(void* const* d_in, const int* in_sizes, int n_in,
                              void* d_out, int out_size, void* d_ws, size_t ws_size,
                              hipStream_t stream) {
    const float* rewards   = (const float*)d_in[0];   // [B,T]
    const float* critic    = (const float*)d_in[1];   // [B,T+1]
    const float* mu        = (const float*)d_in[2];   // [B,T,A]
    const float* sigma     = (const float*)d_in[3];
    const float* old_mu    = (const float*)d_in[4];
    const float* old_sigma = (const float*)d_in[5];
    const float* actions   = (const float*)d_in[6];
    const int*   dones     = (const int*)d_in[7];     // [B,T]
    float* out = (float*)d_out;

    double* partials = (double*)d_ws;                 // NB1 * 8 B = 16 KB

    gae_obj_kernel<<<NB1, 512, 0, stream>>>(rewards, critic, dones,
                                            mu, sigma, old_mu, old_sigma,
                                            actions, partials);
    out_kernel<<<NB3, 256, 0, stream>>>(sigma, partials, out);
}